// Round 2
// baseline (820.160 us; speedup 1.0000x reference)
//
#include <hip/hip_runtime.h>
#include <hip/hip_bf16.h>
#include <cstdint>

#define NEG (-1.0e30f)

typedef unsigned short u16;
typedef __attribute__((ext_vector_type(8))) short short8;
typedef __attribute__((ext_vector_type(4))) float f32x4;

typedef const __attribute__((address_space(1))) void cg_void;
typedef __attribute__((address_space(3))) void lds_void;

// dims
#define Bsz   32
#define Tlen  1000
#define Cdim  512
#define Vdim  2000
#define Udim  100
#define Mrows (Bsz * Tlen)   // 32000
#define Npad  2048

// ws layout (bytes)
#define WS_ABF 0u
#define WS_WBF 32768000u                    // a_bf: 32000*512*2
#define WS_Z   (WS_WBF + 2097152u)          // w_bf: 2048*512*2
#define WS_C   (WS_Z + 128000000u)          // Z: 32000*2000*2
#define WS_ACC (WS_C + 128000u)             // c: 32000*4; accum: 2 floats

__device__ inline u16 f2bf(float x) {
  uint32_t u = __float_as_uint(x);
  uint32_t r = (u + 0x7fffu + ((u >> 16) & 1u)) >> 16;
  return (u16)r;
}
__device__ inline float bf2f(u16 u) {
  return __uint_as_float(((uint32_t)u) << 16);
}

__device__ inline float waveMax(float v) {
  #pragma unroll
  for (int o = 32; o > 0; o >>= 1) v = fmaxf(v, __shfl_down(v, o));
  return v;
}
__device__ inline float waveSum(float v) {
  #pragma unroll
  for (int o = 32; o > 0; o >>= 1) v += __shfl_down(v, o);
  return v;
}

__device__ inline float lse2(float a, float b) {
  float m = fmaxf(a, b);
  return m + logf(expf(a - m) + expf(b - m));
}
__device__ inline float lse3(float a, float b, float c) {
  float m = fmaxf(a, fmaxf(b, c));
  return m + logf(expf(a - m) + expf(b - m) + expf(c - m));
}

// ---------------- K1: fp32 -> bf16 conversion (+ zero accumulators) --------
__global__ void convert_kernel(const float* __restrict__ enc, const float* __restrict__ W,
                               u16* __restrict__ a_bf, u16* __restrict__ w_bf,
                               float* __restrict__ accum) {
  int idx = blockIdx.x * blockDim.x + threadIdx.x;
  int stride = gridDim.x * blockDim.x;
  if (idx == 0) { accum[0] = 0.0f; accum[1] = 0.0f; }
  for (int i = idx; i < Mrows * Cdim; i += stride) a_bf[i] = f2bf(enc[i]);
  for (int i = idx; i < Npad * Cdim; i += stride)
    w_bf[i] = (i < Vdim * Cdim) ? f2bf(W[i]) : (u16)0;
}

// ---------------- K2: bf16 GEMM (A: 32000x512, W: 2048x512, C = A*W^T) -----
// 128x128 tile, BK=64, 4 waves each computing 64x64 via 16x16x32 MFMA.
// global_load_lds width=16, XOR swizzle (chunk ^= row&7) for conflict-free
// ds_read_b128.
__global__ __launch_bounds__(256) void gemm_kernel(const u16* __restrict__ A,
                                                   const u16* __restrict__ Wb,
                                                   u16* __restrict__ Z) {
  __shared__ __attribute__((aligned(16))) u16 As[128 * 64];
  __shared__ __attribute__((aligned(16))) u16 Bs[128 * 64];
  const int tid = threadIdx.x;
  const int wave = tid >> 6;
  const int lane = tid & 63;
  const int nBase = blockIdx.x * 128;
  const int mBase = blockIdx.y * 128;
  const int m_lane = lane & 15;
  const int quad = lane >> 4;

  f32x4 acc[4][4];
  const f32x4 zero4 = {0.0f, 0.0f, 0.0f, 0.0f};
  #pragma unroll
  for (int i = 0; i < 4; ++i)
    #pragma unroll
    for (int j = 0; j < 4; ++j) acc[i][j] = zero4;

  for (int k0 = 0; k0 < Cdim; k0 += 64) {
    #pragma unroll
    for (int r = 0; r < 4; ++r) {
      int u = r * 256 + tid;
      int g = u >> 3;                 // tile row 0..127
      int q = (u & 7) ^ (g & 7);      // logical 16B chunk to fetch
      const u16* gpA = A + ((size_t)(mBase + g) << 9) + (k0 + (q << 3));
      __builtin_amdgcn_global_load_lds((cg_void*)gpA, (lds_void*)&As[(r * 4 + wave) * 512],
                                       16, 0, 0);
      const u16* gpB = Wb + ((size_t)(nBase + g) << 9) + (k0 + (q << 3));
      __builtin_amdgcn_global_load_lds((cg_void*)gpB, (lds_void*)&Bs[(r * 4 + wave) * 512],
                                       16, 0, 0);
    }
    __syncthreads();
    #pragma unroll
    for (int kk = 0; kk < 2; ++kk) {
      short8 af[4], bfv[4];
      #pragma unroll
      for (int mi = 0; mi < 4; ++mi) {
        int row = (wave >> 1) * 64 + mi * 16 + m_lane;
        int q = (kk * 4 + quad) ^ (row & 7);
        af[mi] = *(const short8*)&As[row * 64 + (q << 3)];
      }
      #pragma unroll
      for (int ni = 0; ni < 4; ++ni) {
        int col = (wave & 1) * 64 + ni * 16 + m_lane;
        int q = (kk * 4 + quad) ^ (col & 7);
        bfv[ni] = *(const short8*)&Bs[col * 64 + (q << 3)];
      }
      #pragma unroll
      for (int mi = 0; mi < 4; ++mi)
        #pragma unroll
        for (int ni = 0; ni < 4; ++ni)
          acc[mi][ni] = __builtin_amdgcn_mfma_f32_16x16x32_bf16(af[mi], bfv[ni],
                                                                acc[mi][ni], 0, 0, 0);
    }
    __syncthreads();
  }
  // epilogue: C/D layout col=lane&15, row=quad*4+reg
  #pragma unroll
  for (int ni = 0; ni < 4; ++ni) {
    int col = nBase + (wave & 1) * 64 + ni * 16 + m_lane;
    if (col < Vdim) {
      #pragma unroll
      for (int mi = 0; mi < 4; ++mi) {
        int row0 = mBase + (wave >> 1) * 64 + mi * 16 + quad * 4;
        #pragma unroll
        for (int rg = 0; rg < 4; ++rg)
          Z[(size_t)(row0 + rg) * Vdim + col] = f2bf(acc[mi][ni][rg]);
      }
    }
  }
}

// ---------------- K3: fused softmax stats + CR loss ------------------------
// One block per (b<16, t) pair. c = max + log(sum exp) for both halves;
// CR pair term = sum_v (p1-p2)*(z1-z2)   (log-denominators cancel exactly).
__global__ __launch_bounds__(256) void cr_stats_kernel(const u16* __restrict__ Z,
                                                       const float* __restrict__ bias,
                                                       const int* __restrict__ lens,
                                                       float* __restrict__ cstat,
                                                       float* __restrict__ accum) {
  int bp = blockIdx.x;   // 0..15
  int t = blockIdx.y;    // 0..999
  int tid = threadIdx.x;
  int wave = tid >> 6, lane = tid & 63;
  size_t r1 = (size_t)bp * Tlen + t;
  size_t r2 = r1 + (size_t)16 * Tlen;
  const u16* z1 = Z + r1 * Vdim;
  const u16* z2 = Z + r2 * Vdim;

  float v1[8], v2[8];
  float mx1 = NEG, mx2 = NEG;
  #pragma unroll
  for (int i = 0; i < 8; ++i) {
    int col = i * 256 + tid;
    if (col < Vdim) {
      float bb = bias[col];
      v1[i] = bf2f(z1[col]) + bb;
      v2[i] = bf2f(z2[col]) + bb;
      mx1 = fmaxf(mx1, v1[i]);
      mx2 = fmaxf(mx2, v2[i]);
    } else { v1[i] = NEG; v2[i] = NEG; }
  }
  __shared__ float red[8];
  float w1 = waveMax(mx1), w2 = waveMax(mx2);
  if (lane == 0) { red[wave] = w1; red[4 + wave] = w2; }
  __syncthreads();
  float M1 = fmaxf(fmaxf(red[0], red[1]), fmaxf(red[2], red[3]));
  float M2 = fmaxf(fmaxf(red[4], red[5]), fmaxf(red[6], red[7]));
  __syncthreads();
  float s1 = 0.0f, s2 = 0.0f;
  #pragma unroll
  for (int i = 0; i < 8; ++i) {
    s1 += expf(v1[i] - M1);   // pad lanes: expf(-1e30)=0
    s2 += expf(v2[i] - M2);
  }
  s1 = waveSum(s1); s2 = waveSum(s2);
  if (lane == 0) { red[wave] = s1; red[4 + wave] = s2; }
  __syncthreads();
  float S1 = red[0] + red[1] + red[2] + red[3];
  float S2 = red[4] + red[5] + red[6] + red[7];
  float c1 = M1 + logf(S1);
  float c2 = M2 + logf(S2);
  if (tid == 0) { cstat[r1] = c1; cstat[r2] = c2; }
  float f = 0.0f;
  #pragma unroll
  for (int i = 0; i < 8; ++i) {
    int col = i * 256 + tid;
    if (col < Vdim) {
      float p1 = expf(v1[i] - c1);
      float p2 = expf(v2[i] - c2);
      f += (p1 - p2) * (v1[i] - v2[i]);   // bias cancels in the difference
    }
  }
  __syncthreads();
  f = waveSum(f);
  if (lane == 0) red[wave] = f;
  __syncthreads();
  if (tid == 0 && t < lens[bp]) {
    atomicAdd(&accum[1], 0.5f * (red[0] + red[1] + red[2] + red[3]));
  }
}

// ---------------- K4: CTC forward scan, one wave per sequence --------------
// States s = 4*lane + j (j=0..3), 256 >= S=201. Neighbors via 2 shfl_up/step.
// Blank log-prob shared by all even states; labels gathered from Z directly.
__global__ __launch_bounds__(64) void ctc_kernel(const u16* __restrict__ Z,
                                                 const float* __restrict__ bias,
                                                 const float* __restrict__ cstat,
                                                 const int* __restrict__ targets,
                                                 const int* __restrict__ lens,
                                                 const int* __restrict__ tlens,
                                                 float* __restrict__ accum) {
  int b = blockIdx.x;
  int lane = threadIdx.x;
  const int* tgt = targets + b * Udim;
  int i1 = min(2 * lane, Udim - 1);
  int i3 = min(2 * lane + 1, Udim - 1);
  int l1 = tgt[i1];
  int l3 = tgt[i3];
  int lm1 = tgt[min(max(2 * lane - 1, 0), Udim - 1)];  // clamped: no OOB read
  bool skip1 = (lane >= 1) && (l1 != lm1);  // s=4*lane+1 (needs s>=3)
  bool skip3 = (l3 != l1);                  // s=4*lane+3 (always >=3)
  float bias0 = bias[0], bias1 = bias[l1], bias3 = bias[l3];
  int len = lens[b];
  int tl = tlens[b];
  const u16* zb = Z + (size_t)b * Tlen * Vdim;
  const float* cb = cstat + (size_t)b * Tlen;

  // t=0
  u16 z0A = zb[0], z1A = zb[l1], z3A = zb[l3];
  float cA = cb[0];
  float a0 = (lane == 0) ? (bf2f(z0A) + bias0 - cA) : NEG;
  float a1 = (lane == 0) ? (bf2f(z1A) + bias1 - cA) : NEG;
  float a2 = NEG, a3 = NEG;

  // prefetch t=1 (stage A) and t=2 (stage B)
  z0A = zb[(size_t)1 * Vdim]; z1A = zb[(size_t)1 * Vdim + l1]; z3A = zb[(size_t)1 * Vdim + l3];
  cA = cb[1];
  u16 z0B = zb[(size_t)2 * Vdim], z1B = zb[(size_t)2 * Vdim + l1], z3B = zb[(size_t)2 * Vdim + l3];
  float cB = cb[2];

  for (int t = 1; t < len; ++t) {
    float lpBk = bf2f(z0A) + bias0 - cA;
    float lp1  = bf2f(z1A) + bias1 - cA;
    float lp3  = bf2f(z3A) + bias3 - cA;
    // rotate prefetch stages; fetch t+2
    z0A = z0B; z1A = z1B; z3A = z3B; cA = cB;
    int tp = min(t + 2, Tlen - 1);
    const u16* zr = zb + (size_t)tp * Vdim;
    z0B = zr[0]; z1B = zr[l1]; z3B = zr[l3]; cB = cb[tp];

    float p3 = __shfl_up(a3, 1);
    float p2 = __shfl_up(a2, 1);
    if (lane == 0) { p3 = NEG; p2 = NEG; }
    float n0 = lse2(a0, p3) + lpBk;                       // even s: no skip
    float n1 = lse3(a1, a0, skip1 ? p3 : NEG) + lp1;
    float n2 = lse2(a2, a1) + lpBk;
    float n3 = lse3(a3, a2, skip3 ? a1 : NEG) + lp3;
    a0 = n0; a1 = n1; a2 = n2; a3 = n3;
  }

  __shared__ float fin[256];
  fin[4 * lane + 0] = a0;
  fin[4 * lane + 1] = a1;
  fin[4 * lane + 2] = a2;
  fin[4 * lane + 3] = a3;
  __syncthreads();
  if (lane == 0) {
    int end = 2 * tl;
    float x = fin[end], y = fin[end - 1];
    float m = fmaxf(x, y);
    float loss = -(m + logf(expf(x - m) + expf(y - m)));
    atomicAdd(&accum[0], 0.5f * loss);
  }
}

// ---------------- K5: finalize to FP32 output ------------------------------
// Output dtype is the reference's output dtype = float32 (two scalars).
__global__ void finalize_kernel(const float* __restrict__ accum, float* __restrict__ out) {
  if (threadIdx.x == 0) {
    out[0] = accum[0];
    out[1] = accum[1];
  }
}

extern "C" void kernel_launch(void* const* d_in, const int* in_sizes, int n_in,
                              void* d_out, int out_size, void* d_ws, size_t ws_size,
                              hipStream_t stream) {
  const float* enc = (const float*)d_in[0];
  const float* W = (const float*)d_in[1];
  const float* bias = (const float*)d_in[2];
  const int* lens = (const int*)d_in[3];
  const int* targets = (const int*)d_in[4];
  const int* tlens = (const int*)d_in[5];

  char* ws = (char*)d_ws;
  u16* a_bf = (u16*)(ws + WS_ABF);
  u16* w_bf = (u16*)(ws + WS_WBF);
  u16* Zb   = (u16*)(ws + WS_Z);
  float* cstat = (float*)(ws + WS_C);
  float* accum = (float*)(ws + WS_ACC);

  hipLaunchKernelGGL(convert_kernel, dim3(2048), dim3(256), 0, stream,
                     enc, W, a_bf, w_bf, accum);
  hipLaunchKernelGGL(gemm_kernel, dim3(16, 250), dim3(256), 0, stream,
                     a_bf, w_bf, Zb);
  hipLaunchKernelGGL(cr_stats_kernel, dim3(16, 1000), dim3(256), 0, stream,
                     Zb, bias, lens, cstat, accum);
  hipLaunchKernelGGL(ctc_kernel, dim3(Bsz), dim3(64), 0, stream,
                     Zb, bias, cstat, targets, lens, tlens, accum);
  hipLaunchKernelGGL(finalize_kernel, dim3(1), dim3(64), 0, stream,
                     accum, (float*)d_out);
}

// Round 3
// 686.513 us; speedup vs baseline: 1.1947x; 1.1947x over previous
//
#include <hip/hip_runtime.h>
#include <hip/hip_bf16.h>
#include <cstdint>

#define NEG (-1.0e30f)
#define INVLN2 1.44269504088896340736f
#define LN2    0.69314718055994530942f

typedef unsigned short u16;
typedef __attribute__((ext_vector_type(8))) short short8;
typedef __attribute__((ext_vector_type(4))) float f32x4;

typedef const __attribute__((address_space(1))) void cg_void;
typedef __attribute__((address_space(3))) void lds_void;

// dims
#define Bsz   32
#define Tlen  1000
#define Cdim  512
#define Vdim  2000
#define Udim  100
#define Mrows (Bsz * Tlen)   // 32000
#define Npad  2048
#define GROW  128            // padded G row (floats): 0..99 labels, 100 blank, pad

// ws layout (bytes). G (16.4 MB) aliases a_bf (32.8 MB): a_bf dead after gemm.
#define WS_ABF 0u
#define WS_G   0u
#define WS_WBF 32768000u                    // a_bf: 32000*512*2
#define WS_Z   (WS_WBF + 2097152u)          // w_bf: 2048*512*2
#define WS_ACC (WS_Z + 128000000u)          // Z: 32000*2000*2; then accum: 2 floats

__device__ inline u16 f2bf(float x) {
  uint32_t u = __float_as_uint(x);
  uint32_t r = (u + 0x7fffu + ((u >> 16) & 1u)) >> 16;
  return (u16)r;
}
__device__ inline float bf2f(u16 u) {
  return __uint_as_float(((uint32_t)u) << 16);
}

__device__ inline float waveMax(float v) {
  #pragma unroll
  for (int o = 32; o > 0; o >>= 1) v = fmaxf(v, __shfl_down(v, o));
  return v;
}
__device__ inline float waveSum(float v) {
  #pragma unroll
  for (int o = 32; o > 0; o >>= 1) v += __shfl_down(v, o);
  return v;
}

// log-sum-exp in log2 space (native v_exp_f32 / v_log_f32, no ln2 fixups)
__device__ inline float lse2_2(float a, float b) {
  float m = fmaxf(a, b);
  return m + log2f(exp2f(a - m) + exp2f(b - m));
}
__device__ inline float lse3_2(float a, float b, float c) {
  float m = fmaxf(a, fmaxf(b, c));
  return m + log2f(exp2f(a - m) + exp2f(b - m) + exp2f(c - m));
}

// ---------------- K1: fp32 -> bf16 conversion, vectorized ------------------
__global__ void convert_kernel(const float4* __restrict__ enc4, const float4* __restrict__ W4,
                               uint4* __restrict__ a4, uint4* __restrict__ w4,
                               float* __restrict__ accum) {
  int idx = blockIdx.x * blockDim.x + threadIdx.x;
  int stride = gridDim.x * blockDim.x;
  if (idx == 0) { accum[0] = 0.0f; accum[1] = 0.0f; }
  const int nA = Mrows * Cdim / 8;       // 2,048,000 groups of 8
  const int nW = Vdim * Cdim / 8;        // 128,000
  const int nWp = Npad * Cdim / 8;       // 131,072
  for (int i = idx; i < nA; i += stride) {
    float4 x = enc4[2 * i], y = enc4[2 * i + 1];
    uint4 o;
    o.x = (uint32_t)f2bf(x.x) | ((uint32_t)f2bf(x.y) << 16);
    o.y = (uint32_t)f2bf(x.z) | ((uint32_t)f2bf(x.w) << 16);
    o.z = (uint32_t)f2bf(y.x) | ((uint32_t)f2bf(y.y) << 16);
    o.w = (uint32_t)f2bf(y.z) | ((uint32_t)f2bf(y.w) << 16);
    a4[i] = o;
  }
  for (int i = idx; i < nWp; i += stride) {
    uint4 o = {0, 0, 0, 0};
    if (i < nW) {
      float4 x = W4[2 * i], y = W4[2 * i + 1];
      o.x = (uint32_t)f2bf(x.x) | ((uint32_t)f2bf(x.y) << 16);
      o.y = (uint32_t)f2bf(x.z) | ((uint32_t)f2bf(x.w) << 16);
      o.z = (uint32_t)f2bf(y.x) | ((uint32_t)f2bf(y.y) << 16);
      o.w = (uint32_t)f2bf(y.z) | ((uint32_t)f2bf(y.w) << 16);
    }
    w4[i] = o;
  }
}

// ---------------- K2: bf16 GEMM (A: 32000x512, W: 2048x512, C = A*W^T) -----
__global__ __launch_bounds__(256) void gemm_kernel(const u16* __restrict__ A,
                                                   const u16* __restrict__ Wb,
                                                   u16* __restrict__ Z) {
  __shared__ __attribute__((aligned(16))) u16 As[128 * 64];
  __shared__ __attribute__((aligned(16))) u16 Bs[128 * 64];
  const int tid = threadIdx.x;
  const int wave = tid >> 6;
  const int lane = tid & 63;
  const int nBase = blockIdx.x * 128;
  const int mBase = blockIdx.y * 128;
  const int m_lane = lane & 15;
  const int quad = lane >> 4;

  f32x4 acc[4][4];
  const f32x4 zero4 = {0.0f, 0.0f, 0.0f, 0.0f};
  #pragma unroll
  for (int i = 0; i < 4; ++i)
    #pragma unroll
    for (int j = 0; j < 4; ++j) acc[i][j] = zero4;

  for (int k0 = 0; k0 < Cdim; k0 += 64) {
    #pragma unroll
    for (int r = 0; r < 4; ++r) {
      int u = r * 256 + tid;
      int g = u >> 3;
      int q = (u & 7) ^ (g & 7);
      const u16* gpA = A + ((size_t)(mBase + g) << 9) + (k0 + (q << 3));
      __builtin_amdgcn_global_load_lds((cg_void*)gpA, (lds_void*)&As[(r * 4 + wave) * 512],
                                       16, 0, 0);
      const u16* gpB = Wb + ((size_t)(nBase + g) << 9) + (k0 + (q << 3));
      __builtin_amdgcn_global_load_lds((cg_void*)gpB, (lds_void*)&Bs[(r * 4 + wave) * 512],
                                       16, 0, 0);
    }
    __syncthreads();
    #pragma unroll
    for (int kk = 0; kk < 2; ++kk) {
      short8 af[4], bfv[4];
      #pragma unroll
      for (int mi = 0; mi < 4; ++mi) {
        int row = (wave >> 1) * 64 + mi * 16 + m_lane;
        int q = (kk * 4 + quad) ^ (row & 7);
        af[mi] = *(const short8*)&As[row * 64 + (q << 3)];
      }
      #pragma unroll
      for (int ni = 0; ni < 4; ++ni) {
        int col = (wave & 1) * 64 + ni * 16 + m_lane;
        int q = (kk * 4 + quad) ^ (col & 7);
        bfv[ni] = *(const short8*)&Bs[col * 64 + (q << 3)];
      }
      #pragma unroll
      for (int mi = 0; mi < 4; ++mi)
        #pragma unroll
        for (int ni = 0; ni < 4; ++ni)
          acc[mi][ni] = __builtin_amdgcn_mfma_f32_16x16x32_bf16(af[mi], bfv[ni],
                                                                acc[mi][ni], 0, 0, 0);
    }
    __syncthreads();
  }
  #pragma unroll
  for (int ni = 0; ni < 4; ++ni) {
    int col = nBase + (wave & 1) * 64 + ni * 16 + m_lane;
    if (col < Vdim) {
      #pragma unroll
      for (int mi = 0; mi < 4; ++mi) {
        int row0 = mBase + (wave >> 1) * 64 + mi * 16 + quad * 4;
        #pragma unroll
        for (int rg = 0; rg < 4; ++rg)
          Z[(size_t)(row0 + rg) * Vdim + col] = f2bf(acc[mi][ni][rg]);
      }
    }
  }
}

// ---------------- K3: fused softmax stats + CR loss + CTC gather -----------
// One block per (b<16, t) pair. Computes c = logsumexp for both halves,
// the CR pair term sum_v (p1-p2)*(z1-z2), AND emits the compact CTC
// log-prob rows G[b][t][*] (log2 space): [0..99]=labels, [100]=blank, pad=0.
__global__ __launch_bounds__(256) void cr_stats_kernel(const u16* __restrict__ Z,
                                                       const float* __restrict__ bias,
                                                       const int* __restrict__ lens,
                                                       const int* __restrict__ targets,
                                                       float* __restrict__ G,
                                                       float* __restrict__ accum) {
  int bp = blockIdx.x;   // 0..15
  int t = blockIdx.y;    // 0..999
  int tid = threadIdx.x;
  int wave = tid >> 6, lane = tid & 63;
  size_t r1 = (size_t)bp * Tlen + t;
  size_t r2 = r1 + (size_t)16 * Tlen;
  const u16* z1 = Z + r1 * Vdim;
  const u16* z2 = Z + r2 * Vdim;

  __shared__ float ls1[Vdim];
  __shared__ float ls2[Vdim];
  __shared__ float red[8];

  float v1[8], v2[8];
  float mx1 = NEG, mx2 = NEG;
  #pragma unroll
  for (int i = 0; i < 8; ++i) {
    int col = i * 256 + tid;
    if (col < Vdim) {
      float bb = bias[col];
      v1[i] = bf2f(z1[col]) + bb;
      v2[i] = bf2f(z2[col]) + bb;
      ls1[col] = v1[i];
      ls2[col] = v2[i];
      mx1 = fmaxf(mx1, v1[i]);
      mx2 = fmaxf(mx2, v2[i]);
    } else { v1[i] = NEG; v2[i] = NEG; }
  }
  float w1 = waveMax(mx1), w2 = waveMax(mx2);
  if (lane == 0) { red[wave] = w1; red[4 + wave] = w2; }
  __syncthreads();
  float M1 = fmaxf(fmaxf(red[0], red[1]), fmaxf(red[2], red[3]));
  float M2 = fmaxf(fmaxf(red[4], red[5]), fmaxf(red[6], red[7]));
  __syncthreads();
  float s1 = 0.0f, s2 = 0.0f;
  #pragma unroll
  for (int i = 0; i < 8; ++i) {
    s1 += expf(v1[i] - M1);
    s2 += expf(v2[i] - M2);
  }
  s1 = waveSum(s1); s2 = waveSum(s2);
  if (lane == 0) { red[wave] = s1; red[4 + wave] = s2; }
  __syncthreads();
  float c1 = M1 + logf(red[0] + red[1] + red[2] + red[3]);
  float c2 = M2 + logf(red[4] + red[5] + red[6] + red[7]);

  // --- emit compact CTC rows (log2 space) for b=bp and b=bp+16 ---
  if (tid < GROW) {
    float* G1 = G + r1 * GROW;
    float* G2 = G + r2 * GROW;
    float g1, g2;
    if (tid < Udim) {
      int i1 = targets[bp * Udim + tid];
      int i2 = targets[(bp + 16) * Udim + tid];
      g1 = (ls1[i1] - c1) * INVLN2;
      g2 = (ls2[i2] - c2) * INVLN2;
    } else if (tid == Udim) {
      g1 = (ls1[0] - c1) * INVLN2;   // blank
      g2 = (ls2[0] - c2) * INVLN2;
    } else {
      g1 = 0.0f; g2 = 0.0f;          // pad (finite)
    }
    G1[tid] = g1;
    G2[tid] = g2;
  }

  // --- CR term ---
  float f = 0.0f;
  #pragma unroll
  for (int i = 0; i < 8; ++i) {
    int col = i * 256 + tid;
    if (col < Vdim) {
      float p1 = expf(v1[i] - c1);
      float p2 = expf(v2[i] - c2);
      f += (p1 - p2) * (v1[i] - v2[i]);
    }
  }
  __syncthreads();
  f = waveSum(f);
  if (lane == 0) red[wave] = f;
  __syncthreads();
  if (tid == 0 && t < lens[bp]) {
    atomicAdd(&accum[1], 0.5f * (red[0] + red[1] + red[2] + red[3]));
  }
}

// ---------------- K4: CTC forward scan, one wave per sequence --------------
// Reads compact G rows (512 B contiguous per step), 8-deep register prefetch.
// States s = 4*lane + j, neighbor via one shfl_up. All alphas in log2 space.
#define PFD 8
__global__ __launch_bounds__(64) void ctc_kernel(const float* __restrict__ G,
                                                 const int* __restrict__ targets,
                                                 const int* __restrict__ lens,
                                                 const int* __restrict__ tlens,
                                                 float* __restrict__ accum) {
  int b = blockIdx.x;
  int lane = threadIdx.x;
  const int* tgt = targets + b * Udim;
  int i1 = min(2 * lane, Udim - 1);
  int i3 = min(2 * lane + 1, Udim - 1);
  int l1 = tgt[i1];
  int l3 = tgt[i3];
  int lm1 = tgt[min(max(2 * lane - 1, 0), Udim - 1)];
  bool skip1 = (lane >= 1) && (l1 != lm1);
  bool skip3 = (l3 != l1);
  int len = lens[b];
  int tl = tlens[b];
  const float* gb = G + (size_t)b * Tlen * GROW;

  // t=0 init (log2 space)
  float a0 = (lane == 0) ? gb[Udim] : NEG;   // blank
  float a1 = (lane == 0) ? gb[0] : NEG;      // first label
  float a2 = NEG, a3 = NEG;

  // prime prefetch: times 1..PFD
  float2 pl[PFD];
  float pb[PFD];
  #pragma unroll
  for (int d = 0; d < PFD; ++d) {
    const float* r = gb + (size_t)(1 + d) * GROW;
    pl[d] = *(const float2*)(r + 2 * lane);
    pb[d] = r[Udim];
  }

  int t = 1;
  while (t + PFD <= len) {
    #pragma unroll
    for (int d = 0; d < PFD; ++d) {
      float lp1 = pl[d].x, lp3 = pl[d].y, lpBk = pb[d];
      float p3 = __shfl_up(a3, 1);
      if (lane == 0) p3 = NEG;
      float n0 = lse2_2(a0, p3) + lpBk;
      float n1 = lse3_2(a1, a0, skip1 ? p3 : NEG) + lp1;
      float n2 = lse2_2(a2, a1) + lpBk;
      float n3 = lse3_2(a3, a2, skip3 ? a1 : NEG) + lp3;
      a0 = n0; a1 = n1; a2 = n2; a3 = n3;
      int tp = min(t + d + PFD, Tlen - 1);
      const float* r = gb + (size_t)tp * GROW;
      pl[d] = *(const float2*)(r + 2 * lane);
      pb[d] = r[Udim];
    }
    t += PFD;
  }
  // tail (< PFD iters; slots already prefetched: slot index (tt-1)&7)
  for (; t < len; ++t) {
    int d = (t - 1) & (PFD - 1);
    float lp1 = pl[d].x, lp3 = pl[d].y, lpBk = pb[d];
    float p3 = __shfl_up(a3, 1);
    if (lane == 0) p3 = NEG;
    float n0 = lse2_2(a0, p3) + lpBk;
    float n1 = lse3_2(a1, a0, skip1 ? p3 : NEG) + lp1;
    float n2 = lse2_2(a2, a1) + lpBk;
    float n3 = lse3_2(a3, a2, skip3 ? a1 : NEG) + lp3;
    a0 = n0; a1 = n1; a2 = n2; a3 = n3;
  }

  __shared__ float fin[256];
  fin[4 * lane + 0] = a0;
  fin[4 * lane + 1] = a1;
  fin[4 * lane + 2] = a2;
  fin[4 * lane + 3] = a3;
  __syncthreads();
  if (lane == 0) {
    int end = 2 * tl;
    float x = fin[end], y = fin[end - 1];
    float m = fmaxf(x, y);
    float loss = -LN2 * (m + log2f(exp2f(x - m) + exp2f(y - m)));
    atomicAdd(&accum[0], 0.5f * loss);
  }
}

// ---------------- K5: finalize to FP32 output ------------------------------
__global__ void finalize_kernel(const float* __restrict__ accum, float* __restrict__ out) {
  if (threadIdx.x == 0) {
    out[0] = accum[0];
    out[1] = accum[1];
  }
}

extern "C" void kernel_launch(void* const* d_in, const int* in_sizes, int n_in,
                              void* d_out, int out_size, void* d_ws, size_t ws_size,
                              hipStream_t stream) {
  const float* enc = (const float*)d_in[0];
  const float* W = (const float*)d_in[1];
  const float* bias = (const float*)d_in[2];
  const int* lens = (const int*)d_in[3];
  const int* targets = (const int*)d_in[4];
  const int* tlens = (const int*)d_in[5];

  char* ws = (char*)d_ws;
  u16* a_bf = (u16*)(ws + WS_ABF);
  u16* w_bf = (u16*)(ws + WS_WBF);
  u16* Zb   = (u16*)(ws + WS_Z);
  float* Gp  = (float*)(ws + WS_G);   // aliases a_bf (dead after gemm)
  float* accum = (float*)(ws + WS_ACC);

  hipLaunchKernelGGL(convert_kernel, dim3(1024), dim3(256), 0, stream,
                     (const float4*)enc, (const float4*)W, (uint4*)a_bf, (uint4*)w_bf, accum);
  hipLaunchKernelGGL(gemm_kernel, dim3(16, 250), dim3(256), 0, stream,
                     a_bf, w_bf, Zb);
  hipLaunchKernelGGL(cr_stats_kernel, dim3(16, 1000), dim3(256), 0, stream,
                     Zb, bias, lens, targets, Gp, accum);
  hipLaunchKernelGGL(ctc_kernel, dim3(Bsz), dim3(64), 0, stream,
                     Gp, targets, lens, tlens, accum);
  hipLaunchKernelGGL(finalize_kernel, dim3(1), dim3(64), 0, stream,
                     accum, (float*)d_out);
}

// Round 4
// 621.315 us; speedup vs baseline: 1.3200x; 1.1049x over previous
//
#include <hip/hip_runtime.h>
#include <hip/hip_bf16.h>
#include <cstdint>

#define NEG (-1.0e30f)
#define INVLN2 1.44269504088896340736f
#define LN2    0.69314718055994530942f

typedef unsigned short u16;
typedef __attribute__((ext_vector_type(8))) short short8;
typedef __attribute__((ext_vector_type(4))) float f32x4;

typedef const __attribute__((address_space(1))) void cg_void;
typedef __attribute__((address_space(3))) void lds_void;

// dims
#define Bsz   32
#define Tlen  1000
#define Cdim  512
#define Vdim  2000
#define Udim  100
#define Mrows (Bsz * Tlen)   // 32000
#define Npad  2048
#define GROW  128            // padded G row (floats): 0..99 labels, 100 blank, pad

// ws layout (bytes). G (16.4 MB) aliases a_bf (32.8 MB): a_bf dead after gemm.
#define WS_ABF 0u
#define WS_G   0u
#define WS_WBF 32768000u                    // a_bf: 32000*512*2
#define WS_Z   (WS_WBF + 2097152u)          // w_bf: 2048*512*2
#define WS_ACC (WS_Z + 128000000u)          // Z: 32000*2000*2; then accum: 2 floats

__device__ inline u16 f2bf(float x) {
  uint32_t u = __float_as_uint(x);
  uint32_t r = (u + 0x7fffu + ((u >> 16) & 1u)) >> 16;
  return (u16)r;
}
__device__ inline float bf2f(u16 u) {
  return __uint_as_float(((uint32_t)u) << 16);
}

__device__ inline float waveMax(float v) {
  #pragma unroll
  for (int o = 32; o > 0; o >>= 1) v = fmaxf(v, __shfl_down(v, o));
  return v;
}
__device__ inline float waveSum(float v) {
  #pragma unroll
  for (int o = 32; o > 0; o >>= 1) v += __shfl_down(v, o);
  return v;
}

// log-sum-exp in log2 space (native v_exp_f32 / v_log_f32)
__device__ inline float lse2_2(float a, float b) {
  float m = fmaxf(a, b);
  return m + log2f(exp2f(a - m) + exp2f(b - m));
}
__device__ inline float lse3_2(float a, float b, float c) {
  float m = fmaxf(a, fmaxf(b, c));
  return m + log2f(exp2f(a - m) + exp2f(b - m) + exp2f(c - m));
}

// shift value from lane-1 into this lane via DPP wave_shr:1 (VALU, no LDS).
// Lane 0 receives `fill` (bound_ctrl=false -> takes `old` operand).
__device__ inline float shiftup1(float x, float fill) {
  int r = __builtin_amdgcn_update_dpp(__float_as_int(fill), __float_as_int(x),
                                      0x138, 0xF, 0xF, false);
  return __int_as_float(r);
}

// ---------------- K1: fp32 -> bf16 conversion, vectorized ------------------
__global__ void convert_kernel(const float4* __restrict__ enc4, const float4* __restrict__ W4,
                               uint4* __restrict__ a4, uint4* __restrict__ w4,
                               float* __restrict__ accum) {
  int idx = blockIdx.x * blockDim.x + threadIdx.x;
  int stride = gridDim.x * blockDim.x;
  if (idx == 0) { accum[0] = 0.0f; accum[1] = 0.0f; }
  const int nA = Mrows * Cdim / 8;
  const int nW = Vdim * Cdim / 8;
  const int nWp = Npad * Cdim / 8;
  for (int i = idx; i < nA; i += stride) {
    float4 x = enc4[2 * i], y = enc4[2 * i + 1];
    uint4 o;
    o.x = (uint32_t)f2bf(x.x) | ((uint32_t)f2bf(x.y) << 16);
    o.y = (uint32_t)f2bf(x.z) | ((uint32_t)f2bf(x.w) << 16);
    o.z = (uint32_t)f2bf(y.x) | ((uint32_t)f2bf(y.y) << 16);
    o.w = (uint32_t)f2bf(y.z) | ((uint32_t)f2bf(y.w) << 16);
    a4[i] = o;
  }
  for (int i = idx; i < nWp; i += stride) {
    uint4 o = {0, 0, 0, 0};
    if (i < nW) {
      float4 x = W4[2 * i], y = W4[2 * i + 1];
      o.x = (uint32_t)f2bf(x.x) | ((uint32_t)f2bf(x.y) << 16);
      o.y = (uint32_t)f2bf(x.z) | ((uint32_t)f2bf(x.w) << 16);
      o.z = (uint32_t)f2bf(y.x) | ((uint32_t)f2bf(y.y) << 16);
      o.w = (uint32_t)f2bf(y.z) | ((uint32_t)f2bf(y.w) << 16);
    }
    w4[i] = o;
  }
}

// ---------------- K2: bf16 GEMM (A: 32000x512, W: 2048x512, C = A*W^T) -----
__global__ __launch_bounds__(256) void gemm_kernel(const u16* __restrict__ A,
                                                   const u16* __restrict__ Wb,
                                                   u16* __restrict__ Z) {
  __shared__ __attribute__((aligned(16))) u16 As[128 * 64];
  __shared__ __attribute__((aligned(16))) u16 Bs[128 * 64];
  const int tid = threadIdx.x;
  const int wave = tid >> 6;
  const int lane = tid & 63;
  const int nBase = blockIdx.x * 128;
  const int mBase = blockIdx.y * 128;
  const int m_lane = lane & 15;
  const int quad = lane >> 4;

  f32x4 acc[4][4];
  const f32x4 zero4 = {0.0f, 0.0f, 0.0f, 0.0f};
  #pragma unroll
  for (int i = 0; i < 4; ++i)
    #pragma unroll
    for (int j = 0; j < 4; ++j) acc[i][j] = zero4;

  for (int k0 = 0; k0 < Cdim; k0 += 64) {
    #pragma unroll
    for (int r = 0; r < 4; ++r) {
      int u = r * 256 + tid;
      int g = u >> 3;
      int q = (u & 7) ^ (g & 7);
      const u16* gpA = A + ((size_t)(mBase + g) << 9) + (k0 + (q << 3));
      __builtin_amdgcn_global_load_lds((cg_void*)gpA, (lds_void*)&As[(r * 4 + wave) * 512],
                                       16, 0, 0);
      const u16* gpB = Wb + ((size_t)(nBase + g) << 9) + (k0 + (q << 3));
      __builtin_amdgcn_global_load_lds((cg_void*)gpB, (lds_void*)&Bs[(r * 4 + wave) * 512],
                                       16, 0, 0);
    }
    __syncthreads();
    #pragma unroll
    for (int kk = 0; kk < 2; ++kk) {
      short8 af[4], bfv[4];
      #pragma unroll
      for (int mi = 0; mi < 4; ++mi) {
        int row = (wave >> 1) * 64 + mi * 16 + m_lane;
        int q = (kk * 4 + quad) ^ (row & 7);
        af[mi] = *(const short8*)&As[row * 64 + (q << 3)];
      }
      #pragma unroll
      for (int ni = 0; ni < 4; ++ni) {
        int col = (wave & 1) * 64 + ni * 16 + m_lane;
        int q = (kk * 4 + quad) ^ (col & 7);
        bfv[ni] = *(const short8*)&Bs[col * 64 + (q << 3)];
      }
      #pragma unroll
      for (int mi = 0; mi < 4; ++mi)
        #pragma unroll
        for (int ni = 0; ni < 4; ++ni)
          acc[mi][ni] = __builtin_amdgcn_mfma_f32_16x16x32_bf16(af[mi], bfv[ni],
                                                                acc[mi][ni], 0, 0, 0);
    }
    __syncthreads();
  }
  #pragma unroll
  for (int ni = 0; ni < 4; ++ni) {
    int col = nBase + (wave & 1) * 64 + ni * 16 + m_lane;
    if (col < Vdim) {
      #pragma unroll
      for (int mi = 0; mi < 4; ++mi) {
        int row0 = mBase + (wave >> 1) * 64 + mi * 16 + quad * 4;
        #pragma unroll
        for (int rg = 0; rg < 4; ++rg)
          Z[(size_t)(row0 + rg) * Vdim + col] = f2bf(acc[mi][ni][rg]);
      }
    }
  }
}

// ---------------- K3: fused softmax stats + CR loss + CTC gather -----------
__global__ __launch_bounds__(256) void cr_stats_kernel(const u16* __restrict__ Z,
                                                       const float* __restrict__ bias,
                                                       const int* __restrict__ lens,
                                                       const int* __restrict__ targets,
                                                       float* __restrict__ G,
                                                       float* __restrict__ accum) {
  int bp = blockIdx.x;   // 0..15
  int t = blockIdx.y;    // 0..999
  int tid = threadIdx.x;
  int wave = tid >> 6, lane = tid & 63;
  size_t r1 = (size_t)bp * Tlen + t;
  size_t r2 = r1 + (size_t)16 * Tlen;
  const u16* z1 = Z + r1 * Vdim;
  const u16* z2 = Z + r2 * Vdim;

  __shared__ float ls1[Vdim];
  __shared__ float ls2[Vdim];
  __shared__ float red[8];

  float v1[8], v2[8];
  float mx1 = NEG, mx2 = NEG;
  #pragma unroll
  for (int i = 0; i < 8; ++i) {
    int col = i * 256 + tid;
    if (col < Vdim) {
      float bb = bias[col];
      v1[i] = bf2f(z1[col]) + bb;
      v2[i] = bf2f(z2[col]) + bb;
      ls1[col] = v1[i];
      ls2[col] = v2[i];
      mx1 = fmaxf(mx1, v1[i]);
      mx2 = fmaxf(mx2, v2[i]);
    } else { v1[i] = NEG; v2[i] = NEG; }
  }
  float w1 = waveMax(mx1), w2 = waveMax(mx2);
  if (lane == 0) { red[wave] = w1; red[4 + wave] = w2; }
  __syncthreads();
  float M1 = fmaxf(fmaxf(red[0], red[1]), fmaxf(red[2], red[3]));
  float M2 = fmaxf(fmaxf(red[4], red[5]), fmaxf(red[6], red[7]));
  __syncthreads();
  float s1 = 0.0f, s2 = 0.0f;
  #pragma unroll
  for (int i = 0; i < 8; ++i) {
    s1 += expf(v1[i] - M1);
    s2 += expf(v2[i] - M2);
  }
  s1 = waveSum(s1); s2 = waveSum(s2);
  if (lane == 0) { red[wave] = s1; red[4 + wave] = s2; }
  __syncthreads();
  float c1 = M1 + logf(red[0] + red[1] + red[2] + red[3]);
  float c2 = M2 + logf(red[4] + red[5] + red[6] + red[7]);

  if (tid < GROW) {
    float* G1 = G + r1 * GROW;
    float* G2 = G + r2 * GROW;
    float g1, g2;
    if (tid < Udim) {
      int i1 = targets[bp * Udim + tid];
      int i2 = targets[(bp + 16) * Udim + tid];
      g1 = (ls1[i1] - c1) * INVLN2;
      g2 = (ls2[i2] - c2) * INVLN2;
    } else if (tid == Udim) {
      g1 = (ls1[0] - c1) * INVLN2;   // blank
      g2 = (ls2[0] - c2) * INVLN2;
    } else {
      g1 = 0.0f; g2 = 0.0f;
    }
    G1[tid] = g1;
    G2[tid] = g2;
  }

  float f = 0.0f;
  #pragma unroll
  for (int i = 0; i < 8; ++i) {
    int col = i * 256 + tid;
    if (col < Vdim) {
      float p1 = expf(v1[i] - c1);
      float p2 = expf(v2[i] - c2);
      f += (p1 - p2) * (v1[i] - v2[i]);
    }
  }
  __syncthreads();
  f = waveSum(f);
  if (lane == 0) red[wave] = f;
  __syncthreads();
  if (tid == 0 && t < lens[bp]) {
    atomicAdd(&accum[1], 0.5f * (red[0] + red[1] + red[2] + red[3]));
  }
}

// ---------------- K4: CTC forward scan, one wave per sequence --------------
// Compact G rows, 8-deep register prefetch (ALL indices static -> stays in
// VGPRs), DPP wave_shr:1 for the lane-1 neighbor (no DS unit in the chain).
// Tail handled by uniform predicated commit; iteration count padded to x8.
#define PFD 8
__global__ __launch_bounds__(64) void ctc_kernel(const float* __restrict__ G,
                                                 const int* __restrict__ targets,
                                                 const int* __restrict__ lens,
                                                 const int* __restrict__ tlens,
                                                 float* __restrict__ accum) {
  int b = blockIdx.x;
  int lane = threadIdx.x;
  const int* tgt = targets + b * Udim;
  int i1 = min(2 * lane, Udim - 1);
  int i3 = min(2 * lane + 1, Udim - 1);
  int l1 = tgt[i1];
  int l3 = tgt[i3];
  int lm1 = tgt[min(max(2 * lane - 1, 0), Udim - 1)];
  bool skip1 = (lane >= 1) && (l1 != lm1);
  bool skip3 = (l3 != l1);
  int len = lens[b];
  int tl = tlens[b];
  const float* gb = G + (size_t)b * Tlen * GROW;

  // t=0 init (log2 space)
  float a0 = (lane == 0) ? gb[Udim] : NEG;
  float a1 = (lane == 0) ? gb[0] : NEG;
  float a2 = NEG, a3 = NEG;

  // prime prefetch: times 1..PFD
  float2 pl[PFD];
  float pb[PFD];
  #pragma unroll
  for (int d = 0; d < PFD; ++d) {
    const float* r = gb + (size_t)(1 + d) * GROW;
    pl[d] = *(const float2*)(r + 2 * lane);
    pb[d] = r[Udim];
  }

  int iters = ((len - 1) + (PFD - 1)) & ~(PFD - 1);   // covers t=1..len-1
  int t = 1;
  for (int blk = 0; blk < iters; blk += PFD) {
    #pragma unroll
    for (int d = 0; d < PFD; ++d) {
      float lp1 = pl[d].x, lp3 = pl[d].y, lpBk = pb[d];
      // issue next prefetch for this slot (time t+d+PFD), static slot index
      int tp = min(t + d + PFD, Tlen - 1);
      const float* r = gb + (size_t)tp * GROW;
      float2 npl = *(const float2*)(r + 2 * lane);
      float npb = r[Udim];

      float p3 = shiftup1(a3, NEG);   // lane-1's a3; lane0 -> NEG
      float n0 = lse2_2(a0, p3) + lpBk;
      float n1 = lse3_2(a1, a0, skip1 ? p3 : NEG) + lp1;
      float n2 = lse2_2(a2, a1) + lpBk;
      float n3 = lse3_2(a3, a2, skip3 ? a1 : NEG) + lp3;
      bool act = (t + d) < len;       // uniform per block
      a0 = act ? n0 : a0;
      a1 = act ? n1 : a1;
      a2 = act ? n2 : a2;
      a3 = act ? n3 : a3;
      pl[d] = npl;
      pb[d] = npb;
    }
    t += PFD;
  }

  __shared__ float fin[256];
  fin[4 * lane + 0] = a0;
  fin[4 * lane + 1] = a1;
  fin[4 * lane + 2] = a2;
  fin[4 * lane + 3] = a3;
  __syncthreads();
  if (lane == 0) {
    int end = 2 * tl;
    float x = fin[end], y = fin[end - 1];
    float m = fmaxf(x, y);
    float loss = -LN2 * (m + log2f(exp2f(x - m) + exp2f(y - m)));
    atomicAdd(&accum[0], 0.5f * loss);
  }
}

// ---------------- K5: finalize to FP32 output ------------------------------
__global__ void finalize_kernel(const float* __restrict__ accum, float* __restrict__ out) {
  if (threadIdx.x == 0) {
    out[0] = accum[0];
    out[1] = accum[1];
  }
}

extern "C" void kernel_launch(void* const* d_in, const int* in_sizes, int n_in,
                              void* d_out, int out_size, void* d_ws, size_t ws_size,
                              hipStream_t stream) {
  const float* enc = (const float*)d_in[0];
  const float* W = (const float*)d_in[1];
  const float* bias = (const float*)d_in[2];
  const int* lens = (const int*)d_in[3];
  const int* targets = (const int*)d_in[4];
  const int* tlens = (const int*)d_in[5];

  char* ws = (char*)d_ws;
  u16* a_bf = (u16*)(ws + WS_ABF);
  u16* w_bf = (u16*)(ws + WS_WBF);
  u16* Zb   = (u16*)(ws + WS_Z);
  float* Gp  = (float*)(ws + WS_G);   // aliases a_bf (dead after gemm)
  float* accum = (float*)(ws + WS_ACC);

  hipLaunchKernelGGL(convert_kernel, dim3(1024), dim3(256), 0, stream,
                     (const float4*)enc, (const float4*)W, (uint4*)a_bf, (uint4*)w_bf, accum);
  hipLaunchKernelGGL(gemm_kernel, dim3(16, 250), dim3(256), 0, stream,
                     a_bf, w_bf, Zb);
  hipLaunchKernelGGL(cr_stats_kernel, dim3(16, 1000), dim3(256), 0, stream,
                     Zb, bias, lens, targets, Gp, accum);
  hipLaunchKernelGGL(ctc_kernel, dim3(Bsz), dim3(64), 0, stream,
                     Gp, targets, lens, tlens, accum);
  hipLaunchKernelGGL(finalize_kernel, dim3(1), dim3(64), 0, stream,
                     accum, (float*)d_out);
}